// Round 14
// baseline (214.887 us; speedup 1.0000x reference)
//
#include <hip/hip_runtime.h>
#include <hip/hip_bf16.h>

#define NN   50000
#define EE   800000
#define INF_ 128
#define HH   16
#define OUTC 300

#define NB   196      // dst buckets: dst>>8, 196*256 = 50176 >= NN
#define CAP  4608     // max edges/bucket (mean 4082, big headroom)
#define CHK  4096     // edges per bplace block
#define GB_  196      // bplace grid: 196*4096 = 802816 >= EE

// converted-weight offsets (words) inside wc
#define W1_OFF   0
#define WL1_OFF  2048
#define B1_OFF   4096
#define BL1_OFF  4112
#define W2_OFF   4128
#define WL2_OFF  4384
#define B2_OFF   4640
#define BL2_OFF  4656
#define WO_OFF   4672
#define BO_OFF   9472
#define WC_TOT   9772

__device__ __forceinline__ float bfu2f(unsigned short u) {
    return __uint_as_float(((unsigned)u) << 16);
}
__device__ __forceinline__ unsigned short f2bfu(float f) {
    __hip_bfloat16 h = __float2bfloat16(f);
    return *reinterpret_cast<unsigned short*>(&h);
}
__device__ __forceinline__ unsigned packbf(float lo, float hi) {
    return (unsigned)f2bfu(lo) | ((unsigned)f2bfu(hi) << 16);
}
__device__ __forceinline__ float cvt1(const void* p, int i, int flag) {
    return flag ? ((const float*)p)[i] : bfu2f(((const unsigned short*)p)[i]);
}
__device__ __forceinline__ float louf(unsigned u) { return __uint_as_float(u << 16); }
__device__ __forceinline__ float hiuf(unsigned u) { return __uint_as_float(u & 0xffff0000u); }

// ---- convert weights to fp32 in ws; embedded dtype-detect (per-block, redundant);
//      block 0 also publishes flag and zeroes gcur ----
__global__ __launch_bounds__(256) void convert_kernel(
    const void* __restrict__ W1, const void* __restrict__ Wl1,
    const void* __restrict__ b1, const void* __restrict__ bl1,
    const void* __restrict__ W2, const void* __restrict__ Wl2,
    const void* __restrict__ b2, const void* __restrict__ bl2,
    const void* __restrict__ Wo, const void* __restrict__ bo,
    const unsigned* __restrict__ xw, int* __restrict__ flagp,
    int* __restrict__ gcur, float* __restrict__ wc)
{
    __shared__ int shits;
    int tid = threadIdx.x;
    if (tid == 0) shits = 0;
    __syncthreads();
    unsigned w = xw[tid];                 // 256 words sampled
    float lo = __uint_as_float(w << 16);
    if (!(fabsf(lo) < 1e4f)) atomicAdd(&shits, 1);
    __syncthreads();
    const int flag = (shits > 8) ? 1 : 0; // 1 => fp32 inputs

    if (blockIdx.x == 0) {
        if (tid == 0) flagp[0] = flag;
        if (tid < NB) gcur[tid] = 0;
    }

    int t = blockIdx.x * 256 + tid;
    if (t >= WC_TOT) return;
    float v;
    if      (t < WL1_OFF) v = cvt1(W1,  t - W1_OFF,  flag);
    else if (t < B1_OFF)  v = cvt1(Wl1, t - WL1_OFF, flag);
    else if (t < BL1_OFF) v = cvt1(b1,  t - B1_OFF,  flag);
    else if (t < W2_OFF)  v = cvt1(bl1, t - BL1_OFF, flag);
    else if (t < WL2_OFF) v = cvt1(W2,  t - W2_OFF,  flag);
    else if (t < B2_OFF)  v = cvt1(Wl2, t - WL2_OFF, flag);
    else if (t < BL2_OFF) v = cvt1(b2,  t - B2_OFF,  flag);
    else if (t < WO_OFF)  v = cvt1(bl2, t - BL2_OFF, flag);
    else if (t < BO_OFF)  v = cvt1(Wo,  t - WO_OFF,  flag);
    else                  v = cvt1(bo,  t - BO_OFF,  flag);
    wc[t] = v;
}

// ---- stage 1: LDS multisplit of edges into 196 dst-buckets.
// Edge packed into ONE u32: src(16) | dlow(8)<<16 | bucket(8)<<24
// (src < 65536, dst = bucket*256 + dlow). Coalesced writes — scattered-4B
// writes cost 64B/line HBM write-allocate (R5 place_kernel: 52.6 MB for
// 3.2 MB payload). ----
__global__ __launch_bounds__(256) void bplace_kernel(
    const int* __restrict__ src, const int* __restrict__ dst,
    int* __restrict__ gcur, unsigned* __restrict__ gpairs)
{
    __shared__ unsigned raw[CHK];         // 16 KB
    __shared__ unsigned srt[CHK];         // 16 KB
    __shared__ int cnt[NB];
    __shared__ int loff[NB];
    __shared__ int cur2[NB];
    __shared__ int gbase[NB];
    __shared__ int sc[256];

    int tid = threadIdx.x;
    int e0 = blockIdx.x * CHK;
    int n = min(CHK, EE - e0);
    if (n <= 0) return;
    for (int t = tid; t < NB; t += 256) cnt[t] = 0;
    __syncthreads();

    for (int j = tid; j < n; j += 256) {
        unsigned s = (unsigned)src[e0 + j];
        unsigned d = (unsigned)dst[e0 + j];
        unsigned b = d >> 8;
        raw[j] = s | ((d & 255u) << 16) | (b << 24);
        atomicAdd(&cnt[b], 1);
    }
    __syncthreads();

    int v = (tid < NB) ? cnt[tid] : 0;
    sc[tid] = v;
    __syncthreads();
    for (int d = 1; d < 256; d <<= 1) {
        int u = (tid >= d) ? sc[tid - d] : 0;
        __syncthreads();
        sc[tid] += u;
        __syncthreads();
    }
    if (tid < NB) { loff[tid] = sc[tid] - v; cur2[tid] = sc[tid] - v; }
    __syncthreads();

    for (int j = tid; j < n; j += 256) {
        unsigned p = raw[j];
        int b = (int)(p >> 24);
        int pos = atomicAdd(&cur2[b], 1);
        srt[pos] = p;
    }
    __syncthreads();

    if (tid < NB) {
        int c = cnt[tid];
        gbase[tid] = c ? atomicAdd(&gcur[tid], c) : 0;
    }
    __syncthreads();

    for (int j = tid; j < n; j += 256) {
        unsigned p = srt[j];
        int b = (int)(p >> 24);
        int pos = gbase[b] + (j - loff[b]);
        if (pos < CAP) gpairs[(size_t)b * CAP + pos] = p;
    }
}

// ---- stage 2 + lin1 FUSED (R10): per-bucket node hist + scan + CSR placement
// + off/dinv, then the lin1 body for the same 256 nodes this block owns
// (block b covers nodes b*256..b*256+255 in both roles; dinv is in-register).
// NOTE: grid-wide sync via hipLaunchCooperativeKernel is BROKEN under this
// harness's graph capture (R9: absmax 7.9) — fusions must be block-local. ----
__global__ __launch_bounds__(256) void cplace_lin1_kernel(
    const unsigned* __restrict__ gpairs, const int* __restrict__ gcur,
    int* __restrict__ off, float* __restrict__ dinv, int* __restrict__ csr_src,
    const void* __restrict__ xp, const float* __restrict__ wc,
    const int* __restrict__ flagp,
    unsigned short* __restrict__ A, unsigned short* __restrict__ B)
{
    __shared__ unsigned pl[CAP];        // 18 KB
    __shared__ float2 sWL[INF_ * HH];   // 16 KB (.x = W1, .y = Wl1)
    __shared__ int sc[256];
    __shared__ int ncnt[256];
    __shared__ int nscan[256];
    __shared__ int ncur[256];
    int b = blockIdx.x, t = threadIdx.x;

    // stage lin1 weights early (first use is after many barriers)
    for (int k = t; k < INF_ * HH; k += 256)
        sWL[k] = make_float2(wc[W1_OFF + k], wc[WL1_OFF + k]);

    // redundant scan of bucket totals -> gb (exclusive prefix of bucket b)
    int bv = (t < NB) ? gcur[t] : 0;
    sc[t] = bv;
    __syncthreads();
    for (int d = 1; d < 256; d <<= 1) {
        int u = (t >= d) ? sc[t - d] : 0;
        __syncthreads();
        sc[t] += u;
        __syncthreads();
    }
    __shared__ int gb_s;
    if (t == b) gb_s = sc[t] - bv;
    if (b == 0 && t == 0) off[NN] = EE;
    ncnt[t] = 0;
    __syncthreads();
    int gb = gb_s;

    int c = min(gcur[b], CAP);
    int nb = b << 8;
    for (int j = t; j < c; j += 256) pl[j] = gpairs[(size_t)b * CAP + j];
    __syncthreads();

    for (int j = t; j < c; j += 256) atomicAdd(&ncnt[(pl[j] >> 16) & 255], 1);
    __syncthreads();

    int v = ncnt[t];
    nscan[t] = v;
    __syncthreads();
    for (int d = 1; d < 256; d <<= 1) {
        int u = (t >= d) ? nscan[t - d] : 0;
        __syncthreads();
        nscan[t] += u;
        __syncthreads();
    }
    int excl = nscan[t] - v;
    ncur[t] = excl;

    int node = nb + t;
    float di = rsqrtf((float)v + 1.0f);
    if (node < NN) {
        off[node] = gb + excl;
        dinv[node] = di;
    }
    __syncthreads();

    for (int j = t; j < c; j += 256) {
        unsigned p = pl[j];
        int d = (int)((p >> 16) & 255);
        int pos = atomicAdd(&ncur[d], 1);
        csr_src[gb + pos] = (int)(p & 0xFFFFu);
    }
    __syncthreads();

    // ---- lin1 body: A = bf16((x@W1)*di), B = bf16(x@Wl1 + bl1) ----
    if (node >= NN) return;
    const int flag = flagp[0];
    int i = node;

    float a[HH], l[HH];
#pragma unroll
    for (int f = 0; f < HH; f++) { a[f] = 0.f; l[f] = 0.f; }

    for (int k0 = 0; k0 < INF_ / 8; k0++) {
        float xv[8];
        if (flag) {
            const float4* xr = (const float4*)((const float*)xp + (size_t)i * INF_);
            float4 r0 = xr[k0 * 2], r1 = xr[k0 * 2 + 1];
            xv[0] = r0.x; xv[1] = r0.y; xv[2] = r0.z; xv[3] = r0.w;
            xv[4] = r1.x; xv[5] = r1.y; xv[6] = r1.z; xv[7] = r1.w;
        } else {
            const uint4* xr = (const uint4*)((const unsigned short*)xp + (size_t)i * INF_);
            uint4 vv = xr[k0];
            unsigned uu[4] = { vv.x, vv.y, vv.z, vv.w };
#pragma unroll
            for (int q = 0; q < 4; q++) {
                xv[q * 2]     = __uint_as_float(uu[q] << 16);
                xv[q * 2 + 1] = __uint_as_float(uu[q] & 0xffff0000u);
            }
        }
#pragma unroll
        for (int jj = 0; jj < 8; jj++) {
            float xj = xv[jj];
            int k = k0 * 8 + jj;
#pragma unroll
            for (int f = 0; f < HH; f++) {
                float2 wv = sWL[k * HH + f];
                a[f] = fmaf(xj, wv.x, a[f]);
                l[f] = fmaf(xj, wv.y, l[f]);
            }
        }
    }
    unsigned pa[8], pb[8];
#pragma unroll
    for (int h = 0; h < 8; h++) {
        pa[h] = packbf(a[2 * h] * di, a[2 * h + 1] * di);
        pb[h] = packbf(l[2 * h] + wc[BL1_OFF + 2 * h],
                       l[2 * h + 1] + wc[BL1_OFF + 2 * h + 1]);
    }
    uint4* Ar = (uint4*)(A + (size_t)i * HH);
    uint4* Br = (uint4*)(B + (size_t)i * HH);
    Ar[0] = make_uint4(pa[0], pa[1], pa[2], pa[3]);
    Ar[1] = make_uint4(pa[4], pa[5], pa[6], pa[7]);
    Br[0] = make_uint4(pb[0], pb[1], pb[2], pb[3]);
    Br[1] = make_uint4(pb[4], pb[5], pb[6], pb[7]);
}

// ---- gather+combine mode 1 (R7 version, best verified).
// Y[i] = bf16( (relu(di*(agg + X[i]) + b) + Y[i]) * di )
__global__ __launch_bounds__(256) void gather_combine_kernel(
    const int* __restrict__ off, const int* __restrict__ csr,
    const float* __restrict__ dinv, const unsigned short* __restrict__ X,
    unsigned short* __restrict__ Y, const float* __restrict__ bias)
{
    int lane = threadIdx.x & 63;
    int w = (blockIdx.x * 256 + threadIdx.x) >> 6;   // wave id, 0..12499
    int n = lane >> 4, j = lane & 15;
    int node = w * 4 + n;                            // 12500*4 = NN exact
    int s0 = off[node], s1 = off[node + 1];
    int deg = s1 - s0;

    int wmax = deg;
    wmax = max(wmax, __shfl_xor(wmax, 16));
    wmax = max(wmax, __shfl_xor(wmax, 32));

    const uint2* X4 = (const uint2*)X;
    float a0 = 0.f, a1 = 0.f, a2 = 0.f, a3 = 0.f;
    int eh = j >> 2, q = j & 3;

    for (int base = 0; base < wmax; base += 16) {
        int p = s0 + base + j;
        int sj = (p < s1) ? csr[p] : 0;
#pragma unroll
        for (int r = 0; r < 4; r++) {
            if (base + r * 4 >= wmax) break;          // wave-uniform skip
            int e = r * 4 + eh;
            int se = __shfl(sj, (n << 4) + e);        // src of edge e, node n
            if (base + e < deg) {
                uint2 v = X4[(size_t)se * 4 + q];
                a0 += louf(v.x); a1 += hiuf(v.x);
                a2 += louf(v.y); a3 += hiuf(v.y);
            }
        }
    }
#pragma unroll
    for (int m = 4; m <= 8; m <<= 1) {
        a0 += __shfl_xor(a0, m);
        a1 += __shfl_xor(a1, m);
        a2 += __shfl_xor(a2, m);
        a3 += __shfl_xor(a3, m);
    }
    if (eh == 0) {    // lanes j = q: features q*4 .. q*4+3 of node
        float di = dinv[node];
        uint2 xv = X4[(size_t)node * 4 + q];
        float x0 = louf(xv.x), x1 = hiuf(xv.x), x2 = louf(xv.y), x3 = hiuf(xv.y);
        uint2 yv = ((const uint2*)Y)[(size_t)node * 4 + q];
        float y0 = louf(yv.x), y1 = hiuf(yv.x), y2 = louf(yv.y), y3 = hiuf(yv.y);
        float o0 = (fmaxf(di * (a0 + x0) + bias[q * 4 + 0], 0.f) + y0) * di;
        float o1 = (fmaxf(di * (a1 + x1) + bias[q * 4 + 1], 0.f) + y1) * di;
        float o2 = (fmaxf(di * (a2 + x2) + bias[q * 4 + 2], 0.f) + y2) * di;
        float o3 = (fmaxf(di * (a3 + x3) + bias[q * 4 + 3], 0.f) + y3) * di;
        ((uint2*)Y)[(size_t)node * 4 + q] = make_uint2(packbf(o0, o1), packbf(o2, o3));
    }
}

// ---- fused: gather mode-0 (layer-1 combine) + lin2, all in registers. ----
__global__ __launch_bounds__(256) void gather_lin2_kernel(
    const int* __restrict__ off, const int* __restrict__ csr,
    const float* __restrict__ dinv, const unsigned short* __restrict__ X,
    const unsigned short* __restrict__ Yin, const float* __restrict__ wc,
    unsigned short* __restrict__ A2, unsigned short* __restrict__ B2)
{
    int lane = threadIdx.x & 63;
    int w = (blockIdx.x * 256 + threadIdx.x) >> 6;
    int n = lane >> 4, j = lane & 15;
    int node = w * 4 + n;
    int s0 = off[node], s1 = off[node + 1];
    int deg = s1 - s0;

    int wmax = deg;
    wmax = max(wmax, __shfl_xor(wmax, 16));
    wmax = max(wmax, __shfl_xor(wmax, 32));

    const uint2* X4 = (const uint2*)X;
    float a0 = 0.f, a1 = 0.f, a2 = 0.f, a3 = 0.f;
    int eh = j >> 2, q = j & 3;

    for (int base = 0; base < wmax; base += 16) {
        int p = s0 + base + j;
        int sj = (p < s1) ? csr[p] : 0;
#pragma unroll
        for (int r = 0; r < 4; r++) {
            if (base + r * 4 >= wmax) break;          // wave-uniform skip
            int e = r * 4 + eh;
            int se = __shfl(sj, (n << 4) + e);
            if (base + e < deg) {
                uint2 v = X4[(size_t)se * 4 + q];
                a0 += louf(v.x); a1 += hiuf(v.x);
                a2 += louf(v.y); a3 += hiuf(v.y);
            }
        }
    }
#pragma unroll
    for (int m = 4; m <= 8; m <<= 1) {
        a0 += __shfl_xor(a0, m);
        a1 += __shfl_xor(a1, m);
        a2 += __shfl_xor(a2, m);
        a3 += __shfl_xor(a3, m);
    }
    // unconditional epilogue: h1 pieces (features q*4..q*4+3) in every lane
    float di = dinv[node];
    uint2 xv = X4[(size_t)node * 4 + q];
    uint2 yv = ((const uint2*)Yin)[(size_t)node * 4 + q];
    float4 bq = ((const float4*)(wc + B1_OFF))[q];
    float o0 = fmaxf(di * (a0 + louf(xv.x)) + bq.x, 0.f) + louf(yv.x);
    float o1 = fmaxf(di * (a1 + hiuf(xv.x)) + bq.y, 0.f) + hiuf(yv.x);
    float o2 = fmaxf(di * (a2 + louf(xv.y)) + bq.z, 0.f) + louf(yv.y);
    float o3 = fmaxf(di * (a3 + hiuf(xv.y)) + bq.w, 0.f) + hiuf(yv.y);

    // lin2: this lane computes feature f of its node
    int f = j;
    float a = 0.f, l = 0.f;
#pragma unroll
    for (int k = 0; k < HH; k++) {
        int srcl = (lane & 48) + (k >> 2);
        float hk;
        if      ((k & 3) == 0) hk = __shfl(o0, srcl);
        else if ((k & 3) == 1) hk = __shfl(o1, srcl);
        else if ((k & 3) == 2) hk = __shfl(o2, srcl);
        else                   hk = __shfl(o3, srcl);
        a = fmaf(hk, wc[W2_OFF  + k * HH + f], a);
        l = fmaf(hk, wc[WL2_OFF + k * HH + f], l);
    }
    A2[(size_t)node * HH + f] = f2bfu(a * di);
    B2[(size_t)node * HH + f] = f2bfu(l + wc[BL2_OFF + f]);
}

// ---- R12 fused: gather mode-2 (output aggregation) + final matmul +
// log_softmax. Unlike R3's failed version: the wave's 4 z-rows are
// REDISTRIBUTED via 16 shfls into the standalone final layout (zf[n] =
// feature lane&15 of node n, fp32), so each Wo float4 load serves all 4
// nodes (NO 4x amplification), and y-regs are allocated only after gather
// state dies (VGPR stays moderate). Deletes the A round-trip + 1 dispatch.
__global__ __launch_bounds__(256) void gather_final_kernel(
    const int* __restrict__ off, const int* __restrict__ csr,
    const float* __restrict__ dinv, const unsigned short* __restrict__ X,
    const float* __restrict__ wc, const int* __restrict__ flagp,
    void* __restrict__ outp)
{
    int lane = threadIdx.x & 63;
    int w = (blockIdx.x * 256 + threadIdx.x) >> 6;
    int n = lane >> 4, j = lane & 15;
    int node = w * 4 + n;
    int s0 = off[node], s1 = off[node + 1];
    int deg = s1 - s0;

    int wmax = deg;
    wmax = max(wmax, __shfl_xor(wmax, 16));
    wmax = max(wmax, __shfl_xor(wmax, 32));

    const uint2* X4 = (const uint2*)X;
    float a0 = 0.f, a1 = 0.f, a2 = 0.f, a3 = 0.f;
    int eh = j >> 2, q = j & 3;

    for (int base = 0; base < wmax; base += 16) {
        int p = s0 + base + j;
        int sj = (p < s1) ? csr[p] : 0;
#pragma unroll
        for (int r = 0; r < 4; r++) {
            if (base + r * 4 >= wmax) break;          // wave-uniform skip
            int e = r * 4 + eh;
            int se = __shfl(sj, (n << 4) + e);
            if (base + e < deg) {
                uint2 v = X4[(size_t)se * 4 + q];
                a0 += louf(v.x); a1 += hiuf(v.x);
                a2 += louf(v.y); a3 += hiuf(v.y);
            }
        }
    }
#pragma unroll
    for (int m = 4; m <= 8; m <<= 1) {
        a0 += __shfl_xor(a0, m);
        a1 += __shfl_xor(a1, m);
        a2 += __shfl_xor(a2, m);
        a3 += __shfl_xor(a3, m);
    }
    // mode-2 epilogue in ALL lanes: z pieces (features q*4..q*4+3) of node
    {
        float di = dinv[node];
        uint2 xv = X4[(size_t)node * 4 + q];
        a0 = di * (a0 + louf(xv.x));
        a1 = di * (a1 + hiuf(xv.x));
        a2 = di * (a2 + louf(xv.y));
        a3 = di * (a3 + hiuf(xv.y));
    }

    // redistribute: zf[m] = feature (lane&15) of node w*4+m (fp32, no bf16
    // round-trip). Feature f lives in register o_{f&3} of lane (m<<4)+(f>>2).
    int f = lane & 15;
    int fq = f >> 2, fm = f & 3;
    float zf[4];
#pragma unroll
    for (int m = 0; m < 4; m++) {
        int srcl = (m << 4) + fq;
        float t0 = __shfl(a0, srcl);
        float t1 = __shfl(a1, srcl);
        float t2 = __shfl(a2, srcl);
        float t3 = __shfl(a3, srcl);
        zf[m] = (fm == 0) ? t0 : (fm == 1) ? t1 : (fm == 2) ? t2 : t3;
    }

    // ---- final body (identical to standalone final_kernel, i0 = w*4) ----
    const float* Wo = wc + WO_OFF;
    const float* bo = wc + BO_OFF;
    const int flag = flagp[0];
    int i0 = w * 4;

    const bool tl = (lane < OUTC - 256);    // 44 tail lanes
    float4 bq = *(const float4*)(bo + lane * 4);
    float bt = tl ? bo[256 + lane] : 0.f;

    float y[4][4], yt[4];
#pragma unroll
    for (int m = 0; m < 4; m++) {
        y[m][0] = bq.x; y[m][1] = bq.y; y[m][2] = bq.z; y[m][3] = bq.w;
        yt[m] = bt;
    }

#pragma unroll
    for (int k = 0; k < HH; k++) {
        const float* wr = Wo + k * OUTC;
        float4 wq = *(const float4*)(wr + lane * 4);
        float wt = tl ? wr[256 + lane] : 0.f;
        float zb[4];
#pragma unroll
        for (int m = 0; m < 4; m++) zb[m] = __shfl(zf[m], k);
#pragma unroll
        for (int m = 0; m < 4; m++) {
            y[m][0] = fmaf(zb[m], wq.x, y[m][0]);
            y[m][1] = fmaf(zb[m], wq.y, y[m][1]);
            y[m][2] = fmaf(zb[m], wq.z, y[m][2]);
            y[m][3] = fmaf(zb[m], wq.w, y[m][3]);
            yt[m]   = fmaf(zb[m], wt,   yt[m]);
        }
    }

#pragma unroll
    for (int m = 0; m < 4; m++) {
        float mx = fmaxf(fmaxf(y[m][0], y[m][1]), fmaxf(y[m][2], y[m][3]));
        if (tl) mx = fmaxf(mx, yt[m]);
#pragma unroll
        for (int o = 32; o > 0; o >>= 1) mx = fmaxf(mx, __shfl_xor(mx, o));
        float s = __expf(y[m][0] - mx) + __expf(y[m][1] - mx)
                + __expf(y[m][2] - mx) + __expf(y[m][3] - mx);
        if (tl) s += __expf(yt[m] - mx);
#pragma unroll
        for (int o = 32; o > 0; o >>= 1) s += __shfl_xor(s, o);
        float lse = mx + __logf(s);

        if (flag) {
            float* orow = (float*)outp + (size_t)(i0 + m) * OUTC;
            *(float4*)(orow + lane * 4) = make_float4(
                y[m][0] - lse, y[m][1] - lse, y[m][2] - lse, y[m][3] - lse);
            if (tl) orow[256 + lane] = yt[m] - lse;
        } else {
            unsigned short* orow = (unsigned short*)outp + (size_t)(i0 + m) * OUTC;
            *(uint2*)(orow + lane * 4) = make_uint2(
                packbf(y[m][0] - lse, y[m][1] - lse),
                packbf(y[m][2] - lse, y[m][3] - lse));
            if (tl) orow[256 + lane] = f2bfu(yt[m] - lse);
        }
    }
}

extern "C" void kernel_launch(void* const* d_in, const int* in_sizes, int n_in,
                              void* d_out, int out_size, void* d_ws, size_t ws_size,
                              hipStream_t stream) {
    const void* x   = d_in[0];
    const int*  ei  = (const int*)d_in[1];
    const void* W1  = d_in[2];
    const void* b1  = d_in[3];
    const void* Wl1 = d_in[4];
    const void* bl1 = d_in[5];
    const void* W2  = d_in[6];
    const void* b2  = d_in[7];
    const void* Wl2 = d_in[8];
    const void* bl2 = d_in[9];
    const void* Wo  = d_in[10];
    const void* bo  = d_in[11];

    const int* srcp = ei;        // edge_index[0]
    const int* dstp = ei + EE;   // edge_index[1]

    // ws layout (4-byte words), all regions 16B-aligned:
    char* wsb = (char*)d_ws;
    int*   flag    = (int*)wsb;                         // word 0
    float* wc      = (float*)(wsb + 4 * 16);            // 16 .. 9788
    int*   gcur    = (int*)(wsb + 4 * 10000);           // 196
    int*   off     = (int*)(wsb + 4 * 10400);           // NN+1 -> .. 60401
    int*   csr_src = (int*)(wsb + 4 * 60416);           // EE -> .. 860416
    float* dinv    = (float*)(wsb + 4 * 860416);        // NN -> .. 910416
    unsigned* gpairs = (unsigned*)(wsb + 4 * 910416);   // NB*CAP words -> .. 1813584
    unsigned short* A  = (unsigned short*)(wsb + 4 * 1813600);  // bf16, 400000 words
    unsigned short* B  = (unsigned short*)(wsb + 4 * 2213600);
    unsigned short* A2 = (unsigned short*)(wsb + 4 * 2613600);
    unsigned short* B2 = (unsigned short*)(wsb + 4 * 3013600);

    const int gG4 = (NN / 4 * 64) / 256;    // 12500 waves -> 3125 blocks
    const int gW  = (WC_TOT + 255) / 256;

    // weights convert + dtype detect + gcur zero (fused)
    convert_kernel<<<gW, 256, 0, stream>>>(W1, Wl1, b1, bl1, W2, Wl2, b2, bl2,
                                           Wo, bo, (const unsigned*)x, flag, gcur, wc);

    // CSR build via LDS multisplit (packed u32 edges); cplace carries lin1
    bplace_kernel<<<GB_, 256, 0, stream>>>(srcp, dstp, gcur, gpairs);
    cplace_lin1_kernel<<<NB, 256, 0, stream>>>(gpairs, gcur, off, dinv, csr_src,
                                               x, wc, flag, A, B);

    // layer 1 combine + lin2 (A,B -> A2,B2)
    gather_lin2_kernel<<<gG4, 256, 0, stream>>>(off, csr_src, dinv, A, B, wc, A2, B2);

    // layer 2 combine: B2 <- (relu(di*(agg(A2)+A2)+b2)+B2)*di
    gather_combine_kernel<<<gG4, 256, 0, stream>>>(off, csr_src, dinv, A2, B2, wc + B2_OFF);

    // output aggregation + final matmul + log_softmax (fused, amplification-free)
    gather_final_kernel<<<gG4, 256, 0, stream>>>(off, csr_src, dinv, B2, wc, flag, d_out);
}

// Round 16
// 205.933 us; speedup vs baseline: 1.0435x; 1.0435x over previous
//
#include <hip/hip_runtime.h>
#include <hip/hip_bf16.h>

#define NN   50000
#define EE   800000
#define INF_ 128
#define HH   16
#define OUTC 300

#define NB   196      // dst buckets: dst>>8, 196*256 = 50176 >= NN
#define CAP  4608     // max edges/bucket (mean 4082, big headroom)
#define CHK  4096     // edges per bplace block
#define GB_  196      // bplace grid: 196*4096 = 802816 >= EE

// converted-weight offsets (words) inside wc
#define W1_OFF   0
#define WL1_OFF  2048
#define B1_OFF   4096
#define BL1_OFF  4112
#define W2_OFF   4128
#define WL2_OFF  4384
#define B2_OFF   4640
#define BL2_OFF  4656
#define WO_OFF   4672
#define BO_OFF   9472
#define WC_TOT   9772

__device__ __forceinline__ float bfu2f(unsigned short u) {
    return __uint_as_float(((unsigned)u) << 16);
}
__device__ __forceinline__ unsigned short f2bfu(float f) {
    __hip_bfloat16 h = __float2bfloat16(f);
    return *reinterpret_cast<unsigned short*>(&h);
}
__device__ __forceinline__ unsigned packbf(float lo, float hi) {
    return (unsigned)f2bfu(lo) | ((unsigned)f2bfu(hi) << 16);
}
__device__ __forceinline__ float cvt1(const void* p, int i, int flag) {
    return flag ? ((const float*)p)[i] : bfu2f(((const unsigned short*)p)[i]);
}
__device__ __forceinline__ float louf(unsigned u) { return __uint_as_float(u << 16); }
__device__ __forceinline__ float hiuf(unsigned u) { return __uint_as_float(u & 0xffff0000u); }

// ---- convert weights to fp32 in ws; embedded dtype-detect (per-block, redundant);
//      block 0 also publishes flag and zeroes gcur ----
__global__ __launch_bounds__(256) void convert_kernel(
    const void* __restrict__ W1, const void* __restrict__ Wl1,
    const void* __restrict__ b1, const void* __restrict__ bl1,
    const void* __restrict__ W2, const void* __restrict__ Wl2,
    const void* __restrict__ b2, const void* __restrict__ bl2,
    const void* __restrict__ Wo, const void* __restrict__ bo,
    const unsigned* __restrict__ xw, int* __restrict__ flagp,
    int* __restrict__ gcur, float* __restrict__ wc)
{
    __shared__ int shits;
    int tid = threadIdx.x;
    if (tid == 0) shits = 0;
    __syncthreads();
    unsigned w = xw[tid];                 // 256 words sampled
    float lo = __uint_as_float(w << 16);
    if (!(fabsf(lo) < 1e4f)) atomicAdd(&shits, 1);
    __syncthreads();
    const int flag = (shits > 8) ? 1 : 0; // 1 => fp32 inputs

    if (blockIdx.x == 0) {
        if (tid == 0) flagp[0] = flag;
        if (tid < NB) gcur[tid] = 0;
    }

    int t = blockIdx.x * 256 + tid;
    if (t >= WC_TOT) return;
    float v;
    if      (t < WL1_OFF) v = cvt1(W1,  t - W1_OFF,  flag);
    else if (t < B1_OFF)  v = cvt1(Wl1, t - WL1_OFF, flag);
    else if (t < BL1_OFF) v = cvt1(b1,  t - B1_OFF,  flag);
    else if (t < W2_OFF)  v = cvt1(bl1, t - BL1_OFF, flag);
    else if (t < WL2_OFF) v = cvt1(W2,  t - W2_OFF,  flag);
    else if (t < B2_OFF)  v = cvt1(Wl2, t - WL2_OFF, flag);
    else if (t < BL2_OFF) v = cvt1(b2,  t - B2_OFF,  flag);
    else if (t < WO_OFF)  v = cvt1(bl2, t - BL2_OFF, flag);
    else if (t < BO_OFF)  v = cvt1(Wo,  t - WO_OFF,  flag);
    else                  v = cvt1(bo,  t - BO_OFF,  flag);
    wc[t] = v;
}

// ---- stage 1: LDS multisplit of edges into 196 dst-buckets.
// Edge packed into ONE u32: src(16) | dlow(8)<<16 | bucket(8)<<24
// (src < 65536, dst = bucket*256 + dlow). Coalesced writes — scattered-4B
// writes cost 64B/line HBM write-allocate (R5 place_kernel: 52.6 MB for
// 3.2 MB payload). ----
__global__ __launch_bounds__(256) void bplace_kernel(
    const int* __restrict__ src, const int* __restrict__ dst,
    int* __restrict__ gcur, unsigned* __restrict__ gpairs)
{
    __shared__ unsigned raw[CHK];         // 16 KB
    __shared__ unsigned srt[CHK];         // 16 KB
    __shared__ int cnt[NB];
    __shared__ int loff[NB];
    __shared__ int cur2[NB];
    __shared__ int gbase[NB];
    __shared__ int sc[256];

    int tid = threadIdx.x;
    int e0 = blockIdx.x * CHK;
    int n = min(CHK, EE - e0);
    if (n <= 0) return;
    for (int t = tid; t < NB; t += 256) cnt[t] = 0;
    __syncthreads();

    for (int j = tid; j < n; j += 256) {
        unsigned s = (unsigned)src[e0 + j];
        unsigned d = (unsigned)dst[e0 + j];
        unsigned b = d >> 8;
        raw[j] = s | ((d & 255u) << 16) | (b << 24);
        atomicAdd(&cnt[b], 1);
    }
    __syncthreads();

    int v = (tid < NB) ? cnt[tid] : 0;
    sc[tid] = v;
    __syncthreads();
    for (int d = 1; d < 256; d <<= 1) {
        int u = (tid >= d) ? sc[tid - d] : 0;
        __syncthreads();
        sc[tid] += u;
        __syncthreads();
    }
    if (tid < NB) { loff[tid] = sc[tid] - v; cur2[tid] = sc[tid] - v; }
    __syncthreads();

    for (int j = tid; j < n; j += 256) {
        unsigned p = raw[j];
        int b = (int)(p >> 24);
        int pos = atomicAdd(&cur2[b], 1);
        srt[pos] = p;
    }
    __syncthreads();

    if (tid < NB) {
        int c = cnt[tid];
        gbase[tid] = c ? atomicAdd(&gcur[tid], c) : 0;
    }
    __syncthreads();

    for (int j = tid; j < n; j += 256) {
        unsigned p = srt[j];
        int b = (int)(p >> 24);
        int pos = gbase[b] + (j - loff[b]);
        if (pos < CAP) gpairs[(size_t)b * CAP + pos] = p;
    }
}

// ---- stage 2 + lin1 FUSED (R10): per-bucket node hist + scan + CSR placement
// + off/dinv, then the lin1 body for the same 256 nodes this block owns
// (block b covers nodes b*256..b*256+255 in both roles; dinv is in-register).
// NOTE: grid-wide sync via hipLaunchCooperativeKernel is BROKEN under this
// harness's graph capture (R9: absmax 7.9) — fusions must be block-local.
// NOTE (R14): heterogeneous-phase fusion into one wave (gather+final) LOSES
// ~7 µs to occupancy/pipelining — keep gather and final as separate kernels. ----
__global__ __launch_bounds__(256) void cplace_lin1_kernel(
    const unsigned* __restrict__ gpairs, const int* __restrict__ gcur,
    int* __restrict__ off, float* __restrict__ dinv, int* __restrict__ csr_src,
    const void* __restrict__ xp, const float* __restrict__ wc,
    const int* __restrict__ flagp,
    unsigned short* __restrict__ A, unsigned short* __restrict__ B)
{
    __shared__ unsigned pl[CAP];        // 18 KB
    __shared__ float2 sWL[INF_ * HH];   // 16 KB (.x = W1, .y = Wl1)
    __shared__ int sc[256];
    __shared__ int ncnt[256];
    __shared__ int nscan[256];
    __shared__ int ncur[256];
    int b = blockIdx.x, t = threadIdx.x;

    // stage lin1 weights early (first use is after many barriers)
    for (int k = t; k < INF_ * HH; k += 256)
        sWL[k] = make_float2(wc[W1_OFF + k], wc[WL1_OFF + k]);

    // redundant scan of bucket totals -> gb (exclusive prefix of bucket b)
    int bv = (t < NB) ? gcur[t] : 0;
    sc[t] = bv;
    __syncthreads();
    for (int d = 1; d < 256; d <<= 1) {
        int u = (t >= d) ? sc[t - d] : 0;
        __syncthreads();
        sc[t] += u;
        __syncthreads();
    }
    __shared__ int gb_s;
    if (t == b) gb_s = sc[t] - bv;
    if (b == 0 && t == 0) off[NN] = EE;
    ncnt[t] = 0;
    __syncthreads();
    int gb = gb_s;

    int c = min(gcur[b], CAP);
    int nb = b << 8;
    for (int j = t; j < c; j += 256) pl[j] = gpairs[(size_t)b * CAP + j];
    __syncthreads();

    for (int j = t; j < c; j += 256) atomicAdd(&ncnt[(pl[j] >> 16) & 255], 1);
    __syncthreads();

    int v = ncnt[t];
    nscan[t] = v;
    __syncthreads();
    for (int d = 1; d < 256; d <<= 1) {
        int u = (t >= d) ? nscan[t - d] : 0;
        __syncthreads();
        nscan[t] += u;
        __syncthreads();
    }
    int excl = nscan[t] - v;
    ncur[t] = excl;

    int node = nb + t;
    float di = rsqrtf((float)v + 1.0f);
    if (node < NN) {
        off[node] = gb + excl;
        dinv[node] = di;
    }
    __syncthreads();

    for (int j = t; j < c; j += 256) {
        unsigned p = pl[j];
        int d = (int)((p >> 16) & 255);
        int pos = atomicAdd(&ncur[d], 1);
        csr_src[gb + pos] = (int)(p & 0xFFFFu);
    }
    __syncthreads();

    // ---- lin1 body: A = bf16((x@W1)*di), B = bf16(x@Wl1 + bl1) ----
    if (node >= NN) return;
    const int flag = flagp[0];
    int i = node;

    float a[HH], l[HH];
#pragma unroll
    for (int f = 0; f < HH; f++) { a[f] = 0.f; l[f] = 0.f; }

    for (int k0 = 0; k0 < INF_ / 8; k0++) {
        float xv[8];
        if (flag) {
            const float4* xr = (const float4*)((const float*)xp + (size_t)i * INF_);
            float4 r0 = xr[k0 * 2], r1 = xr[k0 * 2 + 1];
            xv[0] = r0.x; xv[1] = r0.y; xv[2] = r0.z; xv[3] = r0.w;
            xv[4] = r1.x; xv[5] = r1.y; xv[6] = r1.z; xv[7] = r1.w;
        } else {
            const uint4* xr = (const uint4*)((const unsigned short*)xp + (size_t)i * INF_);
            uint4 vv = xr[k0];
            unsigned uu[4] = { vv.x, vv.y, vv.z, vv.w };
#pragma unroll
            for (int q = 0; q < 4; q++) {
                xv[q * 2]     = __uint_as_float(uu[q] << 16);
                xv[q * 2 + 1] = __uint_as_float(uu[q] & 0xffff0000u);
            }
        }
#pragma unroll
        for (int jj = 0; jj < 8; jj++) {
            float xj = xv[jj];
            int k = k0 * 8 + jj;
#pragma unroll
            for (int f = 0; f < HH; f++) {
                float2 wv = sWL[k * HH + f];
                a[f] = fmaf(xj, wv.x, a[f]);
                l[f] = fmaf(xj, wv.y, l[f]);
            }
        }
    }
    unsigned pa[8], pb[8];
#pragma unroll
    for (int h = 0; h < 8; h++) {
        pa[h] = packbf(a[2 * h] * di, a[2 * h + 1] * di);
        pb[h] = packbf(l[2 * h] + wc[BL1_OFF + 2 * h],
                       l[2 * h + 1] + wc[BL1_OFF + 2 * h + 1]);
    }
    uint4* Ar = (uint4*)(A + (size_t)i * HH);
    uint4* Br = (uint4*)(B + (size_t)i * HH);
    Ar[0] = make_uint4(pa[0], pa[1], pa[2], pa[3]);
    Ar[1] = make_uint4(pa[4], pa[5], pa[6], pa[7]);
    Br[0] = make_uint4(pb[0], pb[1], pb[2], pb[3]);
    Br[1] = make_uint4(pb[4], pb[5], pb[6], pb[7]);
}

// ---- generic gather+combine (modes 1 and 2), R7 version (best verified).
// mode 1: Y[i] = bf16( (relu(di*(agg + X[i]) + b) + Y[i]) * di )
// mode 2: Y[i] = bf16( di*(agg + X[i]) )
__global__ __launch_bounds__(256) void gather_combine_kernel(
    const int* __restrict__ off, const int* __restrict__ csr,
    const float* __restrict__ dinv, const unsigned short* __restrict__ X,
    unsigned short* __restrict__ Y, const float* __restrict__ bias, int mode)
{
    int lane = threadIdx.x & 63;
    int w = (blockIdx.x * 256 + threadIdx.x) >> 6;   // wave id, 0..12499
    int n = lane >> 4, j = lane & 15;
    int node = w * 4 + n;                            // 12500*4 = NN exact
    int s0 = off[node], s1 = off[node + 1];
    int deg = s1 - s0;

    int wmax = deg;
    wmax = max(wmax, __shfl_xor(wmax, 16));
    wmax = max(wmax, __shfl_xor(wmax, 32));

    const uint2* X4 = (const uint2*)X;
    float a0 = 0.f, a1 = 0.f, a2 = 0.f, a3 = 0.f;
    int eh = j >> 2, q = j & 3;

    for (int base = 0; base < wmax; base += 16) {
        int p = s0 + base + j;
        int sj = (p < s1) ? csr[p] : 0;
#pragma unroll
        for (int r = 0; r < 4; r++) {
            if (base + r * 4 >= wmax) break;          // wave-uniform skip
            int e = r * 4 + eh;
            int se = __shfl(sj, (n << 4) + e);        // src of edge e, node n
            if (base + e < deg) {
                uint2 v = X4[(size_t)se * 4 + q];
                a0 += louf(v.x); a1 += hiuf(v.x);
                a2 += louf(v.y); a3 += hiuf(v.y);
            }
        }
    }
#pragma unroll
    for (int m = 4; m <= 8; m <<= 1) {
        a0 += __shfl_xor(a0, m);
        a1 += __shfl_xor(a1, m);
        a2 += __shfl_xor(a2, m);
        a3 += __shfl_xor(a3, m);
    }
    if (eh == 0) {    // lanes j = q: features q*4 .. q*4+3 of node
        float di = dinv[node];
        uint2 xv = X4[(size_t)node * 4 + q];
        float x0 = louf(xv.x), x1 = hiuf(xv.x), x2 = louf(xv.y), x3 = hiuf(xv.y);
        float o0, o1, o2, o3;
        if (mode == 2) {
            o0 = di * (a0 + x0); o1 = di * (a1 + x1);
            o2 = di * (a2 + x2); o3 = di * (a3 + x3);
        } else {
            uint2 yv = ((const uint2*)Y)[(size_t)node * 4 + q];
            float y0 = louf(yv.x), y1 = hiuf(yv.x), y2 = louf(yv.y), y3 = hiuf(yv.y);
            o0 = fmaxf(di * (a0 + x0) + bias[q * 4 + 0], 0.f) + y0;
            o1 = fmaxf(di * (a1 + x1) + bias[q * 4 + 1], 0.f) + y1;
            o2 = fmaxf(di * (a2 + x2) + bias[q * 4 + 2], 0.f) + y2;
            o3 = fmaxf(di * (a3 + x3) + bias[q * 4 + 3], 0.f) + y3;
            if (mode) { o0 *= di; o1 *= di; o2 *= di; o3 *= di; }
        }
        ((uint2*)Y)[(size_t)node * 4 + q] = make_uint2(packbf(o0, o1), packbf(o2, o3));
    }
}

// ---- fused: gather mode-0 (layer-1 combine) + lin2, all in registers. ----
__global__ __launch_bounds__(256) void gather_lin2_kernel(
    const int* __restrict__ off, const int* __restrict__ csr,
    const float* __restrict__ dinv, const unsigned short* __restrict__ X,
    const unsigned short* __restrict__ Yin, const float* __restrict__ wc,
    unsigned short* __restrict__ A2, unsigned short* __restrict__ B2)
{
    int lane = threadIdx.x & 63;
    int w = (blockIdx.x * 256 + threadIdx.x) >> 6;
    int n = lane >> 4, j = lane & 15;
    int node = w * 4 + n;
    int s0 = off[node], s1 = off[node + 1];
    int deg = s1 - s0;

    int wmax = deg;
    wmax = max(wmax, __shfl_xor(wmax, 16));
    wmax = max(wmax, __shfl_xor(wmax, 32));

    const uint2* X4 = (const uint2*)X;
    float a0 = 0.f, a1 = 0.f, a2 = 0.f, a3 = 0.f;
    int eh = j >> 2, q = j & 3;

    for (int base = 0; base < wmax; base += 16) {
        int p = s0 + base + j;
        int sj = (p < s1) ? csr[p] : 0;
#pragma unroll
        for (int r = 0; r < 4; r++) {
            if (base + r * 4 >= wmax) break;          // wave-uniform skip
            int e = r * 4 + eh;
            int se = __shfl(sj, (n << 4) + e);
            if (base + e < deg) {
                uint2 v = X4[(size_t)se * 4 + q];
                a0 += louf(v.x); a1 += hiuf(v.x);
                a2 += louf(v.y); a3 += hiuf(v.y);
            }
        }
    }
#pragma unroll
    for (int m = 4; m <= 8; m <<= 1) {
        a0 += __shfl_xor(a0, m);
        a1 += __shfl_xor(a1, m);
        a2 += __shfl_xor(a2, m);
        a3 += __shfl_xor(a3, m);
    }
    // unconditional epilogue: h1 pieces (features q*4..q*4+3) in every lane
    float di = dinv[node];
    uint2 xv = X4[(size_t)node * 4 + q];
    uint2 yv = ((const uint2*)Yin)[(size_t)node * 4 + q];
    float4 bq = ((const float4*)(wc + B1_OFF))[q];
    float o0 = fmaxf(di * (a0 + louf(xv.x)) + bq.x, 0.f) + louf(yv.x);
    float o1 = fmaxf(di * (a1 + hiuf(xv.x)) + bq.y, 0.f) + hiuf(yv.x);
    float o2 = fmaxf(di * (a2 + louf(xv.y)) + bq.z, 0.f) + louf(yv.y);
    float o3 = fmaxf(di * (a3 + hiuf(xv.y)) + bq.w, 0.f) + hiuf(yv.y);

    // lin2: this lane computes feature f of its node
    int f = j;
    float a = 0.f, l = 0.f;
#pragma unroll
    for (int k = 0; k < HH; k++) {
        int srcl = (lane & 48) + (k >> 2);
        float hk;
        if      ((k & 3) == 0) hk = __shfl(o0, srcl);
        else if ((k & 3) == 1) hk = __shfl(o1, srcl);
        else if ((k & 3) == 2) hk = __shfl(o2, srcl);
        else                   hk = __shfl(o3, srcl);
        a = fmaf(hk, wc[W2_OFF  + k * HH + f], a);
        l = fmaf(hk, wc[WL2_OFF + k * HH + f], l);
    }
    A2[(size_t)node * HH + f] = f2bfu(a * di);
    B2[(size_t)node * HH + f] = f2bfu(l + wc[BL2_OFF + f]);
}

// ---- final (streaming, 4 nodes per wave): y = z@Wo + bo, log_softmax ----
// No LDS: Wo (19.2 KB) fits in the 32 KB per-CU L1 and is reused by ~12
// blocks/CU. Lane owns classes j = lane*4..lane*4+3 (float4, rows 1200 B =
// 16B-aligned) + tail class 256+lane (lanes 0..43). Each Wo load serves all
// 4 nodes (register reuse). Keep SEPARATE from the gather (R3: 4x load
// amplification; R14: fused version = 54.9 µs vs ~48 split). ----
__global__ __launch_bounds__(256) void final_kernel(
    const unsigned short* __restrict__ Z, const float* __restrict__ wc,
    const int* __restrict__ flagp, void* __restrict__ outp)
{
    const float* Wo = wc + WO_OFF;
    const float* bo = wc + BO_OFF;
    const int flag = flagp[0];
    int wave = threadIdx.x >> 6, lane = threadIdx.x & 63;
    int i0 = blockIdx.x * 16 + wave * 4;    // 3125 blocks * 16 = 50000 exact

    float zf[4];
#pragma unroll
    for (int n = 0; n < 4; n++) zf[n] = bfu2f(Z[(size_t)(i0 + n) * HH + (lane & 15)]);

    const bool tl = (lane < OUTC - 256);    // 44 tail lanes
    float4 bq = *(const float4*)(bo + lane * 4);
    float bt = tl ? bo[256 + lane] : 0.f;

    float y[4][4], yt[4];
#pragma unroll
    for (int n = 0; n < 4; n++) {
        y[n][0] = bq.x; y[n][1] = bq.y; y[n][2] = bq.z; y[n][3] = bq.w;
        yt[n] = bt;
    }

#pragma unroll
    for (int k = 0; k < HH; k++) {
        const float* wr = Wo + k * OUTC;
        float4 wq = *(const float4*)(wr + lane * 4);
        float wt = tl ? wr[256 + lane] : 0.f;
        float zb[4];
#pragma unroll
        for (int n = 0; n < 4; n++) zb[n] = __shfl(zf[n], k);
#pragma unroll
        for (int n = 0; n < 4; n++) {
            y[n][0] = fmaf(zb[n], wq.x, y[n][0]);
            y[n][1] = fmaf(zb[n], wq.y, y[n][1]);
            y[n][2] = fmaf(zb[n], wq.z, y[n][2]);
            y[n][3] = fmaf(zb[n], wq.w, y[n][3]);
            yt[n]   = fmaf(zb[n], wt,   yt[n]);
        }
    }

#pragma unroll
    for (int n = 0; n < 4; n++) {
        float m = fmaxf(fmaxf(y[n][0], y[n][1]), fmaxf(y[n][2], y[n][3]));
        if (tl) m = fmaxf(m, yt[n]);
#pragma unroll
        for (int o = 32; o > 0; o >>= 1) m = fmaxf(m, __shfl_xor(m, o));
        float s = __expf(y[n][0] - m) + __expf(y[n][1] - m)
                + __expf(y[n][2] - m) + __expf(y[n][3] - m);
        if (tl) s += __expf(yt[n] - m);
#pragma unroll
        for (int o = 32; o > 0; o >>= 1) s += __shfl_xor(s, o);
        float lse = m + __logf(s);

        if (flag) {
            float* orow = (float*)outp + (size_t)(i0 + n) * OUTC;
            *(float4*)(orow + lane * 4) = make_float4(
                y[n][0] - lse, y[n][1] - lse, y[n][2] - lse, y[n][3] - lse);
            if (tl) orow[256 + lane] = yt[n] - lse;
        } else {
            unsigned short* orow = (unsigned short*)outp + (size_t)(i0 + n) * OUTC;
            *(uint2*)(orow + lane * 4) = make_uint2(
                packbf(y[n][0] - lse, y[n][1] - lse),
                packbf(y[n][2] - lse, y[n][3] - lse));
            if (tl) orow[256 + lane] = f2bfu(yt[n] - lse);
        }
    }
}

extern "C" void kernel_launch(void* const* d_in, const int* in_sizes, int n_in,
                              void* d_out, int out_size, void* d_ws, size_t ws_size,
                              hipStream_t stream) {
    const void* x   = d_in[0];
    const int*  ei  = (const int*)d_in[1];
    const void* W1  = d_in[2];
    const void* b1  = d_in[3];
    const void* Wl1 = d_in[4];
    const void* bl1 = d_in[5];
    const void* W2  = d_in[6];
    const void* b2  = d_in[7];
    const void* Wl2 = d_in[8];
    const void* bl2 = d_in[9];
    const void* Wo  = d_in[10];
    const void* bo  = d_in[11];

    const int* srcp = ei;        // edge_index[0]
    const int* dstp = ei + EE;   // edge_index[1]

    // ws layout (4-byte words), all regions 16B-aligned:
    char* wsb = (char*)d_ws;
    int*   flag    = (int*)wsb;                         // word 0
    float* wc      = (float*)(wsb + 4 * 16);            // 16 .. 9788
    int*   gcur    = (int*)(wsb + 4 * 10000);           // 196
    int*   off     = (int*)(wsb + 4 * 10400);           // NN+1 -> .. 60401
    int*   csr_src = (int*)(wsb + 4 * 60416);           // EE -> .. 860416
    float* dinv    = (float*)(wsb + 4 * 860416);        // NN -> .. 910416
    unsigned* gpairs = (unsigned*)(wsb + 4 * 910416);   // NB*CAP words -> .. 1813584
    unsigned short* A  = (unsigned short*)(wsb + 4 * 1813600);  // bf16, 400000 words
    unsigned short* B  = (unsigned short*)(wsb + 4 * 2213600);
    unsigned short* A2 = (unsigned short*)(wsb + 4 * 2613600);
    unsigned short* B2 = (unsigned short*)(wsb + 4 * 3013600);

    const int gG4 = (NN / 4 * 64) / 256;    // 12500 waves -> 3125 blocks
    const int gW  = (WC_TOT + 255) / 256;

    // weights convert + dtype detect + gcur zero (fused)
    convert_kernel<<<gW, 256, 0, stream>>>(W1, Wl1, b1, bl1, W2, Wl2, b2, bl2,
                                           Wo, bo, (const unsigned*)x, flag, gcur, wc);

    // CSR build via LDS multisplit (packed u32 edges); cplace carries lin1
    bplace_kernel<<<GB_, 256, 0, stream>>>(srcp, dstp, gcur, gpairs);
    cplace_lin1_kernel<<<NB, 256, 0, stream>>>(gpairs, gcur, off, dinv, csr_src,
                                               x, wc, flag, A, B);

    // layer 1 combine + lin2 (A,B -> A2,B2)
    gather_lin2_kernel<<<gG4, 256, 0, stream>>>(off, csr_src, dinv, A, B, wc, A2, B2);

    // layer 2 combine: B2 <- (relu(di*(agg(A2)+A2)+b2)+B2)*di
    gather_combine_kernel<<<gG4, 256, 0, stream>>>(off, csr_src, dinv, A2, B2, wc + B2_OFF, 1);

    // output aggregation: A <- z = dinv*(agg(B2) + B2)
    gather_combine_kernel<<<gG4, 256, 0, stream>>>(off, csr_src, dinv, B2, A, wc + B2_OFF, 2);

    // final matmul + log_softmax (streaming, 4-node-batched)
    final_kernel<<<gG4, 256, 0, stream>>>(A, wc, flag, d_out);
}

// Round 17
// 205.429 us; speedup vs baseline: 1.0460x; 1.0025x over previous
//
#include <hip/hip_runtime.h>
#include <hip/hip_bf16.h>

#define NN   50000
#define EE   800000
#define INF_ 128
#define HH   16
#define OUTC 300

#define NB   196      // dst buckets: dst>>8, 196*256 = 50176 >= NN
#define CAP  4608     // max edges/bucket (mean 4082, big headroom)
#define CHK  4096     // edges per bplace block
#define GB_  196      // bplace grid: 196*4096 = 802816 >= EE

// converted-weight offsets (words) inside wc
#define W1_OFF   0
#define WL1_OFF  2048
#define B1_OFF   4096
#define BL1_OFF  4112
#define W2_OFF   4128
#define WL2_OFF  4384
#define B2_OFF   4640
#define BL2_OFF  4656
#define WO_OFF   4672
#define BO_OFF   9472
#define WC_TOT   9772

__device__ __forceinline__ float bfu2f(unsigned short u) {
    return __uint_as_float(((unsigned)u) << 16);
}
__device__ __forceinline__ unsigned short f2bfu(float f) {
    __hip_bfloat16 h = __float2bfloat16(f);
    return *reinterpret_cast<unsigned short*>(&h);
}
__device__ __forceinline__ unsigned packbf(float lo, float hi) {
    return (unsigned)f2bfu(lo) | ((unsigned)f2bfu(hi) << 16);
}
__device__ __forceinline__ float cvt1(const void* p, int i, int flag) {
    return flag ? ((const float*)p)[i] : bfu2f(((const unsigned short*)p)[i]);
}
__device__ __forceinline__ float louf(unsigned u) { return __uint_as_float(u << 16); }
__device__ __forceinline__ float hiuf(unsigned u) { return __uint_as_float(u & 0xffff0000u); }

// ---- convert weights to fp32 in ws; embedded dtype-detect (per-block, redundant);
//      block 0 also publishes flag and zeroes gcur ----
__global__ __launch_bounds__(256) void convert_kernel(
    const void* __restrict__ W1, const void* __restrict__ Wl1,
    const void* __restrict__ b1, const void* __restrict__ bl1,
    const void* __restrict__ W2, const void* __restrict__ Wl2,
    const void* __restrict__ b2, const void* __restrict__ bl2,
    const void* __restrict__ Wo, const void* __restrict__ bo,
    const unsigned* __restrict__ xw, int* __restrict__ flagp,
    int* __restrict__ gcur, float* __restrict__ wc)
{
    __shared__ int shits;
    int tid = threadIdx.x;
    if (tid == 0) shits = 0;
    __syncthreads();
    unsigned w = xw[tid];                 // 256 words sampled
    float lo = __uint_as_float(w << 16);
    if (!(fabsf(lo) < 1e4f)) atomicAdd(&shits, 1);
    __syncthreads();
    const int flag = (shits > 8) ? 1 : 0; // 1 => fp32 inputs

    if (blockIdx.x == 0) {
        if (tid == 0) flagp[0] = flag;
        if (tid < NB) gcur[tid] = 0;
    }

    int t = blockIdx.x * 256 + tid;
    if (t >= WC_TOT) return;
    float v;
    if      (t < WL1_OFF) v = cvt1(W1,  t - W1_OFF,  flag);
    else if (t < B1_OFF)  v = cvt1(Wl1, t - WL1_OFF, flag);
    else if (t < BL1_OFF) v = cvt1(b1,  t - B1_OFF,  flag);
    else if (t < W2_OFF)  v = cvt1(bl1, t - BL1_OFF, flag);
    else if (t < WL2_OFF) v = cvt1(W2,  t - W2_OFF,  flag);
    else if (t < B2_OFF)  v = cvt1(Wl2, t - WL2_OFF, flag);
    else if (t < BL2_OFF) v = cvt1(b2,  t - B2_OFF,  flag);
    else if (t < WO_OFF)  v = cvt1(bl2, t - BL2_OFF, flag);
    else if (t < BO_OFF)  v = cvt1(Wo,  t - WO_OFF,  flag);
    else                  v = cvt1(bo,  t - BO_OFF,  flag);
    wc[t] = v;
}

// ---- stage 1: LDS multisplit of edges into 196 dst-buckets.
// Edge packed into ONE u32: src(16) | dlow(8)<<16 | bucket(8)<<24
// (src < 65536, dst = bucket*256 + dlow). Coalesced writes — scattered-4B
// writes cost 64B/line HBM write-allocate (R5 place_kernel: 52.6 MB for
// 3.2 MB payload). ----
__global__ __launch_bounds__(256) void bplace_kernel(
    const int* __restrict__ src, const int* __restrict__ dst,
    int* __restrict__ gcur, unsigned* __restrict__ gpairs)
{
    __shared__ unsigned raw[CHK];         // 16 KB
    __shared__ unsigned srt[CHK];         // 16 KB
    __shared__ int cnt[NB];
    __shared__ int loff[NB];
    __shared__ int cur2[NB];
    __shared__ int gbase[NB];
    __shared__ int sc[256];

    int tid = threadIdx.x;
    int e0 = blockIdx.x * CHK;
    int n = min(CHK, EE - e0);
    if (n <= 0) return;
    for (int t = tid; t < NB; t += 256) cnt[t] = 0;
    __syncthreads();

    for (int j = tid; j < n; j += 256) {
        unsigned s = (unsigned)src[e0 + j];
        unsigned d = (unsigned)dst[e0 + j];
        unsigned b = d >> 8;
        raw[j] = s | ((d & 255u) << 16) | (b << 24);
        atomicAdd(&cnt[b], 1);
    }
    __syncthreads();

    int v = (tid < NB) ? cnt[tid] : 0;
    sc[tid] = v;
    __syncthreads();
    for (int d = 1; d < 256; d <<= 1) {
        int u = (tid >= d) ? sc[tid - d] : 0;
        __syncthreads();
        sc[tid] += u;
        __syncthreads();
    }
    if (tid < NB) { loff[tid] = sc[tid] - v; cur2[tid] = sc[tid] - v; }
    __syncthreads();

    for (int j = tid; j < n; j += 256) {
        unsigned p = raw[j];
        int b = (int)(p >> 24);
        int pos = atomicAdd(&cur2[b], 1);
        srt[pos] = p;
    }
    __syncthreads();

    if (tid < NB) {
        int c = cnt[tid];
        gbase[tid] = c ? atomicAdd(&gcur[tid], c) : 0;
    }
    __syncthreads();

    for (int j = tid; j < n; j += 256) {
        unsigned p = srt[j];
        int b = (int)(p >> 24);
        int pos = gbase[b] + (j - loff[b]);
        if (pos < CAP) gpairs[(size_t)b * CAP + pos] = p;
    }
}

// ---- stage 2 + lin1 FUSED (R10): per-bucket node hist + scan + CSR placement
// + off/dinv, then the lin1 body for the same 256 nodes this block owns
// (block b covers nodes b*256..b*256+255 in both roles; dinv is in-register).
// NOTE: grid-wide sync via hipLaunchCooperativeKernel is BROKEN under this
// harness's graph capture (R9: absmax 7.9) — fusions must be block-local.
// NOTE (R14): heterogeneous-phase fusion into one wave (gather+final) LOSES
// ~7 µs to occupancy/pipelining — keep gather and final as separate kernels. ----
__global__ __launch_bounds__(256) void cplace_lin1_kernel(
    const unsigned* __restrict__ gpairs, const int* __restrict__ gcur,
    int* __restrict__ off, float* __restrict__ dinv, int* __restrict__ csr_src,
    const void* __restrict__ xp, const float* __restrict__ wc,
    const int* __restrict__ flagp,
    unsigned short* __restrict__ A, unsigned short* __restrict__ B)
{
    __shared__ unsigned pl[CAP];        // 18 KB
    __shared__ float2 sWL[INF_ * HH];   // 16 KB (.x = W1, .y = Wl1)
    __shared__ int sc[256];
    __shared__ int ncnt[256];
    __shared__ int nscan[256];
    __shared__ int ncur[256];
    int b = blockIdx.x, t = threadIdx.x;

    // stage lin1 weights early (first use is after many barriers)
    for (int k = t; k < INF_ * HH; k += 256)
        sWL[k] = make_float2(wc[W1_OFF + k], wc[WL1_OFF + k]);

    // redundant scan of bucket totals -> gb (exclusive prefix of bucket b)
    int bv = (t < NB) ? gcur[t] : 0;
    sc[t] = bv;
    __syncthreads();
    for (int d = 1; d < 256; d <<= 1) {
        int u = (t >= d) ? sc[t - d] : 0;
        __syncthreads();
        sc[t] += u;
        __syncthreads();
    }
    __shared__ int gb_s;
    if (t == b) gb_s = sc[t] - bv;
    if (b == 0 && t == 0) off[NN] = EE;
    ncnt[t] = 0;
    __syncthreads();
    int gb = gb_s;

    int c = min(gcur[b], CAP);
    int nb = b << 8;
    for (int j = t; j < c; j += 256) pl[j] = gpairs[(size_t)b * CAP + j];
    __syncthreads();

    for (int j = t; j < c; j += 256) atomicAdd(&ncnt[(pl[j] >> 16) & 255], 1);
    __syncthreads();

    int v = ncnt[t];
    nscan[t] = v;
    __syncthreads();
    for (int d = 1; d < 256; d <<= 1) {
        int u = (t >= d) ? nscan[t - d] : 0;
        __syncthreads();
        nscan[t] += u;
        __syncthreads();
    }
    int excl = nscan[t] - v;
    ncur[t] = excl;

    int node = nb + t;
    float di = rsqrtf((float)v + 1.0f);
    if (node < NN) {
        off[node] = gb + excl;
        dinv[node] = di;
    }
    __syncthreads();

    for (int j = t; j < c; j += 256) {
        unsigned p = pl[j];
        int d = (int)((p >> 16) & 255);
        int pos = atomicAdd(&ncur[d], 1);
        csr_src[gb + pos] = (int)(p & 0xFFFFu);
    }
    __syncthreads();

    // ---- lin1 body: A = bf16((x@W1)*di), B = bf16(x@Wl1 + bl1) ----
    if (node >= NN) return;
    const int flag = flagp[0];
    int i = node;

    float a[HH], l[HH];
#pragma unroll
    for (int f = 0; f < HH; f++) { a[f] = 0.f; l[f] = 0.f; }

    for (int k0 = 0; k0 < INF_ / 8; k0++) {
        float xv[8];
        if (flag) {
            const float4* xr = (const float4*)((const float*)xp + (size_t)i * INF_);
            float4 r0 = xr[k0 * 2], r1 = xr[k0 * 2 + 1];
            xv[0] = r0.x; xv[1] = r0.y; xv[2] = r0.z; xv[3] = r0.w;
            xv[4] = r1.x; xv[5] = r1.y; xv[6] = r1.z; xv[7] = r1.w;
        } else {
            const uint4* xr = (const uint4*)((const unsigned short*)xp + (size_t)i * INF_);
            uint4 vv = xr[k0];
            unsigned uu[4] = { vv.x, vv.y, vv.z, vv.w };
#pragma unroll
            for (int q = 0; q < 4; q++) {
                xv[q * 2]     = __uint_as_float(uu[q] << 16);
                xv[q * 2 + 1] = __uint_as_float(uu[q] & 0xffff0000u);
            }
        }
#pragma unroll
        for (int jj = 0; jj < 8; jj++) {
            float xj = xv[jj];
            int k = k0 * 8 + jj;
#pragma unroll
            for (int f = 0; f < HH; f++) {
                float2 wv = sWL[k * HH + f];
                a[f] = fmaf(xj, wv.x, a[f]);
                l[f] = fmaf(xj, wv.y, l[f]);
            }
        }
    }
    unsigned pa[8], pb[8];
#pragma unroll
    for (int h = 0; h < 8; h++) {
        pa[h] = packbf(a[2 * h] * di, a[2 * h + 1] * di);
        pb[h] = packbf(l[2 * h] + wc[BL1_OFF + 2 * h],
                       l[2 * h + 1] + wc[BL1_OFF + 2 * h + 1]);
    }
    uint4* Ar = (uint4*)(A + (size_t)i * HH);
    uint4* Br = (uint4*)(B + (size_t)i * HH);
    Ar[0] = make_uint4(pa[0], pa[1], pa[2], pa[3]);
    Ar[1] = make_uint4(pa[4], pa[5], pa[6], pa[7]);
    Br[0] = make_uint4(pb[0], pb[1], pb[2], pb[3]);
    Br[1] = make_uint4(pb[4], pb[5], pb[6], pb[7]);
}

// ---- generic gather+combine (modes 1 and 2), R7 version (best verified).
// mode 1: Y[i] = bf16( (relu(di*(agg + X[i]) + b) + Y[i]) * di )
// mode 2: Y[i] = bf16( di*(agg + X[i]) )
__global__ __launch_bounds__(256) void gather_combine_kernel(
    const int* __restrict__ off, const int* __restrict__ csr,
    const float* __restrict__ dinv, const unsigned short* __restrict__ X,
    unsigned short* __restrict__ Y, const float* __restrict__ bias, int mode)
{
    int lane = threadIdx.x & 63;
    int w = (blockIdx.x * 256 + threadIdx.x) >> 6;   // wave id, 0..12499
    int n = lane >> 4, j = lane & 15;
    int node = w * 4 + n;                            // 12500*4 = NN exact
    int s0 = off[node], s1 = off[node + 1];
    int deg = s1 - s0;

    int wmax = deg;
    wmax = max(wmax, __shfl_xor(wmax, 16));
    wmax = max(wmax, __shfl_xor(wmax, 32));

    const uint2* X4 = (const uint2*)X;
    float a0 = 0.f, a1 = 0.f, a2 = 0.f, a3 = 0.f;
    int eh = j >> 2, q = j & 3;

    for (int base = 0; base < wmax; base += 16) {
        int p = s0 + base + j;
        int sj = (p < s1) ? csr[p] : 0;
#pragma unroll
        for (int r = 0; r < 4; r++) {
            if (base + r * 4 >= wmax) break;          // wave-uniform skip
            int e = r * 4 + eh;
            int se = __shfl(sj, (n << 4) + e);        // src of edge e, node n
            if (base + e < deg) {
                uint2 v = X4[(size_t)se * 4 + q];
                a0 += louf(v.x); a1 += hiuf(v.x);
                a2 += louf(v.y); a3 += hiuf(v.y);
            }
        }
    }
#pragma unroll
    for (int m = 4; m <= 8; m <<= 1) {
        a0 += __shfl_xor(a0, m);
        a1 += __shfl_xor(a1, m);
        a2 += __shfl_xor(a2, m);
        a3 += __shfl_xor(a3, m);
    }
    if (eh == 0) {    // lanes j = q: features q*4 .. q*4+3 of node
        float di = dinv[node];
        uint2 xv = X4[(size_t)node * 4 + q];
        float x0 = louf(xv.x), x1 = hiuf(xv.x), x2 = louf(xv.y), x3 = hiuf(xv.y);
        float o0, o1, o2, o3;
        if (mode == 2) {
            o0 = di * (a0 + x0); o1 = di * (a1 + x1);
            o2 = di * (a2 + x2); o3 = di * (a3 + x3);
        } else {
            uint2 yv = ((const uint2*)Y)[(size_t)node * 4 + q];
            float y0 = louf(yv.x), y1 = hiuf(yv.x), y2 = louf(yv.y), y3 = hiuf(yv.y);
            o0 = fmaxf(di * (a0 + x0) + bias[q * 4 + 0], 0.f) + y0;
            o1 = fmaxf(di * (a1 + x1) + bias[q * 4 + 1], 0.f) + y1;
            o2 = fmaxf(di * (a2 + x2) + bias[q * 4 + 2], 0.f) + y2;
            o3 = fmaxf(di * (a3 + x3) + bias[q * 4 + 3], 0.f) + y3;
            if (mode) { o0 *= di; o1 *= di; o2 *= di; o3 *= di; }
        }
        ((uint2*)Y)[(size_t)node * 4 + q] = make_uint2(packbf(o0, o1), packbf(o2, o3));
    }
}

// ---- fused: gather mode-0 (layer-1 combine) + lin2, all in registers. ----
__global__ __launch_bounds__(256) void gather_lin2_kernel(
    const int* __restrict__ off, const int* __restrict__ csr,
    const float* __restrict__ dinv, const unsigned short* __restrict__ X,
    const unsigned short* __restrict__ Yin, const float* __restrict__ wc,
    unsigned short* __restrict__ A2, unsigned short* __restrict__ B2)
{
    int lane = threadIdx.x & 63;
    int w = (blockIdx.x * 256 + threadIdx.x) >> 6;
    int n = lane >> 4, j = lane & 15;
    int node = w * 4 + n;
    int s0 = off[node], s1 = off[node + 1];
    int deg = s1 - s0;

    int wmax = deg;
    wmax = max(wmax, __shfl_xor(wmax, 16));
    wmax = max(wmax, __shfl_xor(wmax, 32));

    const uint2* X4 = (const uint2*)X;
    float a0 = 0.f, a1 = 0.f, a2 = 0.f, a3 = 0.f;
    int eh = j >> 2, q = j & 3;

    for (int base = 0; base < wmax; base += 16) {
        int p = s0 + base + j;
        int sj = (p < s1) ? csr[p] : 0;
#pragma unroll
        for (int r = 0; r < 4; r++) {
            if (base + r * 4 >= wmax) break;          // wave-uniform skip
            int e = r * 4 + eh;
            int se = __shfl(sj, (n << 4) + e);
            if (base + e < deg) {
                uint2 v = X4[(size_t)se * 4 + q];
                a0 += louf(v.x); a1 += hiuf(v.x);
                a2 += louf(v.y); a3 += hiuf(v.y);
            }
        }
    }
#pragma unroll
    for (int m = 4; m <= 8; m <<= 1) {
        a0 += __shfl_xor(a0, m);
        a1 += __shfl_xor(a1, m);
        a2 += __shfl_xor(a2, m);
        a3 += __shfl_xor(a3, m);
    }
    // unconditional epilogue: h1 pieces (features q*4..q*4+3) in every lane
    float di = dinv[node];
    uint2 xv = X4[(size_t)node * 4 + q];
    uint2 yv = ((const uint2*)Yin)[(size_t)node * 4 + q];
    float4 bq = ((const float4*)(wc + B1_OFF))[q];
    float o0 = fmaxf(di * (a0 + louf(xv.x)) + bq.x, 0.f) + louf(yv.x);
    float o1 = fmaxf(di * (a1 + hiuf(xv.x)) + bq.y, 0.f) + hiuf(yv.x);
    float o2 = fmaxf(di * (a2 + louf(xv.y)) + bq.z, 0.f) + louf(yv.y);
    float o3 = fmaxf(di * (a3 + hiuf(xv.y)) + bq.w, 0.f) + hiuf(yv.y);

    // lin2: this lane computes feature f of its node
    int f = j;
    float a = 0.f, l = 0.f;
#pragma unroll
    for (int k = 0; k < HH; k++) {
        int srcl = (lane & 48) + (k >> 2);
        float hk;
        if      ((k & 3) == 0) hk = __shfl(o0, srcl);
        else if ((k & 3) == 1) hk = __shfl(o1, srcl);
        else if ((k & 3) == 2) hk = __shfl(o2, srcl);
        else                   hk = __shfl(o3, srcl);
        a = fmaf(hk, wc[W2_OFF  + k * HH + f], a);
        l = fmaf(hk, wc[WL2_OFF + k * HH + f], l);
    }
    A2[(size_t)node * HH + f] = f2bfu(a * di);
    B2[(size_t)node * HH + f] = f2bfu(l + wc[BL2_OFF + f]);
}

// ---- final (streaming): y = z@Wo + bo, log_softmax.
// R16: 2 nodes per wave (was 4) — final_kernel measured 44 µs at VGPR 104 /
// 17% occupancy, latency-bound (writes at 1.3 TB/s, VALUBusy 23%). Halving
// per-wave state (zf[2], y[2][4]) cuts VGPR and the per-wave serial path
// (k-loop FMA depth, softmax DS chains, stores) while doubling wave count
// (25000 waves) for latency hiding. Wo is L1-resident; per-wave Wo traffic
// is constant so aggregate L1 traffic doubles (~500 MB ≈ 13 µs) — still
// far below target. Keep SEPARATE from the gather (R3/R14 lessons). ----
__global__ __launch_bounds__(256) void final_kernel(
    const unsigned short* __restrict__ Z, const float* __restrict__ wc,
    const int* __restrict__ flagp, void* __restrict__ outp)
{
    const float* Wo = wc + WO_OFF;
    const float* bo = wc + BO_OFF;
    const int flag = flagp[0];
    int wave = threadIdx.x >> 6, lane = threadIdx.x & 63;
    int i0 = blockIdx.x * 8 + wave * 2;    // 6250 blocks * 8 = 50000 exact

    float zf[2];
#pragma unroll
    for (int n = 0; n < 2; n++) zf[n] = bfu2f(Z[(size_t)(i0 + n) * HH + (lane & 15)]);

    const bool tl = (lane < OUTC - 256);    // 44 tail lanes
    float4 bq = *(const float4*)(bo + lane * 4);
    float bt = tl ? bo[256 + lane] : 0.f;

    float y[2][4], yt[2];
#pragma unroll
    for (int n = 0; n < 2; n++) {
        y[n][0] = bq.x; y[n][1] = bq.y; y[n][2] = bq.z; y[n][3] = bq.w;
        yt[n] = bt;
    }

#pragma unroll
    for (int k = 0; k < HH; k++) {
        const float* wr = Wo + k * OUTC;
        float4 wq = *(const float4*)(wr + lane * 4);
        float wt = tl ? wr[256 + lane] : 0.f;
        float zb[2];
#pragma unroll
        for (int n = 0; n < 2; n++) zb[n] = __shfl(zf[n], k);
#pragma unroll
        for (int n = 0; n < 2; n++) {
            y[n][0] = fmaf(zb[n], wq.x, y[n][0]);
            y[n][1] = fmaf(zb[n], wq.y, y[n][1]);
            y[n][2] = fmaf(zb[n], wq.z, y[n][2]);
            y[n][3] = fmaf(zb[n], wq.w, y[n][3]);
            yt[n]   = fmaf(zb[n], wt,   yt[n]);
        }
    }

#pragma unroll
    for (int n = 0; n < 2; n++) {
        float m = fmaxf(fmaxf(y[n][0], y[n][1]), fmaxf(y[n][2], y[n][3]));
        if (tl) m = fmaxf(m, yt[n]);
#pragma unroll
        for (int o = 32; o > 0; o >>= 1) m = fmaxf(m, __shfl_xor(m, o));
        float s = __expf(y[n][0] - m) + __expf(y[n][1] - m)
                + __expf(y[n][2] - m) + __expf(y[n][3] - m);
        if (tl) s += __expf(yt[n] - m);
#pragma unroll
        for (int o = 32; o > 0; o >>= 1) s += __shfl_xor(s, o);
        float lse = m + __logf(s);

        if (flag) {
            float* orow = (float*)outp + (size_t)(i0 + n) * OUTC;
            *(float4*)(orow + lane * 4) = make_float4(
                y[n][0] - lse, y[n][1] - lse, y[n][2] - lse, y[n][3] - lse);
            if (tl) orow[256 + lane] = yt[n] - lse;
        } else {
            unsigned short* orow = (unsigned short*)outp + (size_t)(i0 + n) * OUTC;
            *(uint2*)(orow + lane * 4) = make_uint2(
                packbf(y[n][0] - lse, y[n][1] - lse),
                packbf(y[n][2] - lse, y[n][3] - lse));
            if (tl) orow[256 + lane] = f2bfu(yt[n] - lse);
        }
    }
}

extern "C" void kernel_launch(void* const* d_in, const int* in_sizes, int n_in,
                              void* d_out, int out_size, void* d_ws, size_t ws_size,
                              hipStream_t stream) {
    const void* x   = d_in[0];
    const int*  ei  = (const int*)d_in[1];
    const void* W1  = d_in[2];
    const void* b1  = d_in[3];
    const void* Wl1 = d_in[4];
    const void* bl1 = d_in[5];
    const void* W2  = d_in[6];
    const void* b2  = d_in[7];
    const void* Wl2 = d_in[8];
    const void* bl2 = d_in[9];
    const void* Wo  = d_in[10];
    const void* bo  = d_in[11];

    const int* srcp = ei;        // edge_index[0]
    const int* dstp = ei + EE;   // edge_index[1]

    // ws layout (4-byte words), all regions 16B-aligned:
    char* wsb = (char*)d_ws;
    int*   flag    = (int*)wsb;                         // word 0
    float* wc      = (float*)(wsb + 4 * 16);            // 16 .. 9788
    int*   gcur    = (int*)(wsb + 4 * 10000);           // 196
    int*   off     = (int*)(wsb + 4 * 10400);           // NN+1 -> .. 60401
    int*   csr_src = (int*)(wsb + 4 * 60416);           // EE -> .. 860416
    float* dinv    = (float*)(wsb + 4 * 860416);        // NN -> .. 910416
    unsigned* gpairs = (unsigned*)(wsb + 4 * 910416);   // NB*CAP words -> .. 1813584
    unsigned short* A  = (unsigned short*)(wsb + 4 * 1813600);  // bf16, 400000 words
    unsigned short* B  = (unsigned short*)(wsb + 4 * 2213600);
    unsigned short* A2 = (unsigned short*)(wsb + 4 * 2613600);
    unsigned short* B2 = (unsigned short*)(wsb + 4 * 3013600);

    const int gG4 = (NN / 4 * 64) / 256;    // 12500 waves -> 3125 blocks
    const int gF  = NN / 8;                 // final: 2 nodes/wave -> 6250 blocks
    const int gW  = (WC_TOT + 255) / 256;

    // weights convert + dtype detect + gcur zero (fused)
    convert_kernel<<<gW, 256, 0, stream>>>(W1, Wl1, b1, bl1, W2, Wl2, b2, bl2,
                                           Wo, bo, (const unsigned*)x, flag, gcur, wc);

    // CSR build via LDS multisplit (packed u32 edges); cplace carries lin1
    bplace_kernel<<<GB_, 256, 0, stream>>>(srcp, dstp, gcur, gpairs);
    cplace_lin1_kernel<<<NB, 256, 0, stream>>>(gpairs, gcur, off, dinv, csr_src,
                                               x, wc, flag, A, B);

    // layer 1 combine + lin2 (A,B -> A2,B2)
    gather_lin2_kernel<<<gG4, 256, 0, stream>>>(off, csr_src, dinv, A, B, wc, A2, B2);

    // layer 2 combine: B2 <- (relu(di*(agg(A2)+A2)+b2)+B2)*di
    gather_combine_kernel<<<gG4, 256, 0, stream>>>(off, csr_src, dinv, A2, B2, wc + B2_OFF, 1);

    // output aggregation: A <- z = dinv*(agg(B2) + B2)
    gather_combine_kernel<<<gG4, 256, 0, stream>>>(off, csr_src, dinv, B2, A, wc + B2_OFF, 2);

    // final matmul + log_softmax (streaming, 2-node-per-wave)
    final_kernel<<<gF, 256, 0, stream>>>(A, wc, flag, d_out);
}